// Round 14
// baseline (378.938 us; speedup 1.0000x reference)
//
#include <hip/hip_runtime.h>
#include <math.h>

// ---------------------------------------------------------------------------
// GCN: x[N,128] -> conv1(W1[128,32]) -> relu -> conv2(W2[32,16]) -> fc heads
// Outputs (concat): r[N], x1f[N]
//
// CSR-pull v12 = verified v9 (350.8 us) + ONE change: epair stream loads in
// both gather kernels are NON-TEMPORAL (gfx950 `nt`). Mechanism: the 25.6 MB
// zero-reuse edge stream was flowing through the same 4 MB per-XCD L2 that
// must hold the 12.8 MB g1 table -> continuous eviction -> 163 MB of L2-miss
// traffic per gather32 dispatch (= its entire 104 us at 1.6 TB/s). nt loads
// keep the stream out of L2, dedicating it to g1/z.
// Round-13 lesson: v11's fusedA/in-place-partB (58 KB LDS) was net negative;
// build restored to v9 exactly.
// Workspace: (66N + 2E + 2K + 2)*4 = 52.0 MB.
// ---------------------------------------------------------------------------

#define TPB 256
#define PA_CHUNK 4096
#define KMAXB 512
#define NPW 8              // nodes per wave in the gather kernels

// 8-byte non-temporal load of an int2 (single dwordx2, nt flag)
__device__ __forceinline__ int2 ntload2(const int2* p) {
    long long v = __builtin_nontemporal_load((const long long*)p);
    int2 r;
    r.x = (int)(v & 0xffffffffLL);
    r.y = (int)(v >> 32);
    return r;
}

// ---------------- phase 1: per-bucket edge counts --------------------------
__global__ __launch_bounds__(512) void countA_kernel(const int* __restrict__ dst,
                                                     int* __restrict__ gtot,
                                                     int E, int K) {
    __shared__ int lhist[KMAXB];
    const int tid = threadIdx.x;
    const int e0  = blockIdx.x * PA_CHUNK;
    if (tid < KMAXB) lhist[tid] = 0;
    __syncthreads();
#pragma unroll
    for (int i = 0; i < 8; ++i) {
        int e = e0 + tid + i * 512;
        if (e < E) atomicAdd(&lhist[dst[e] >> 8], 1);
    }
    __syncthreads();
    if (tid < K && lhist[tid] > 0) atomicAdd(&gtot[tid], lhist[tid]);
}

// ------- phase 2: scan totals -> gstart[K+1]; gcursor = gstart -------------
__global__ __launch_bounds__(64) void kscan_kernel(const int* __restrict__ gtot,
                                                   int* __restrict__ gstart,
                                                   int* __restrict__ gcursor,
                                                   int K, int E) {
    int tid = threadIdx.x;                  // one wave
    int b0 = tid * 8, v[8], s = 0;
#pragma unroll
    for (int t = 0; t < 8; ++t) {
        v[t] = s;
        int idx = b0 + t;
        s += (idx < K) ? gtot[idx] : 0;
    }
    int incl = s;
#pragma unroll
    for (int d = 1; d < 64; d <<= 1) {
        int t2 = __shfl_up(incl, d);
        if (tid >= d) incl += t2;
    }
    int excl = incl - s;
#pragma unroll
    for (int t = 0; t < 8; ++t) {
        int idx = b0 + t;
        if (idx < K) { gstart[idx] = excl + v[t]; gcursor[idx] = excl + v[t]; }
    }
    if (tid == 63) gstart[K] = E;
}

// ---------- phase 3: place edges into bucket-contiguous tmp ----------------
__global__ __launch_bounds__(512) void placeA_kernel(const int* __restrict__ src,
                                                     const int* __restrict__ dst,
                                                     const float* __restrict__ ew,
                                                     uint2* __restrict__ tmp,
                                                     int* __restrict__ gcursor,
                                                     int E, int K) {
    __shared__ int lhist[KMAXB], lbase[KMAXB], lcur[KMAXB], gbaseS[KMAXB];
    __shared__ int ltot;
    __shared__ uint2 stage[PA_CHUNK];
    __shared__ int   saddr[PA_CHUNK];
    const int tid = threadIdx.x;
    const int e0  = blockIdx.x * PA_CHUNK;

    if (tid < KMAXB) { lhist[tid] = 0; lcur[tid] = 0; }
    __syncthreads();

    int   b[8];
    uint2 p[8];
#pragma unroll
    for (int i = 0; i < 8; ++i) {
        int e = e0 + tid + i * 512;
        b[i] = -1;
        if (e < E) {
            int d   = dst[e];
            int s   = src[e];
            float w = ew[e];
            b[i]   = d >> 8;
            p[i].x = __float_as_uint(w);
            p[i].y = ((unsigned)s << 8) | (unsigned)(d & 255);
            atomicAdd(&lhist[b[i]], 1);
        }
    }
    __syncthreads();

    // exclusive scan lhist -> lbase (single wave, 8 bins/lane over 512)
    if (tid < 64) {
        int b0 = tid * 8, v[8], s = 0;
#pragma unroll
        for (int t = 0; t < 8; ++t) { v[t] = s; s += lhist[b0 + t]; }
        int incl = s;
#pragma unroll
        for (int d = 1; d < 64; d <<= 1) {
            int t2 = __shfl_up(incl, d);
            if (tid >= d) incl += t2;
        }
        int excl = incl - s;
#pragma unroll
        for (int t = 0; t < 8; ++t) lbase[b0 + t] = excl + v[t];
        if (tid == 63) ltot = incl;
    }
    __syncthreads();

    // reserve ABSOLUTE ranges from the based cursor (coalesced atomics)
    if (tid < K && lhist[tid] > 0)
        gbaseS[tid] = atomicAdd(&gcursor[tid], lhist[tid]);
    __syncthreads();

    // rank within (block,bucket), stage into LDS with absolute address
#pragma unroll
    for (int i = 0; i < 8; ++i) {
        if (b[i] >= 0) {
            int r    = atomicAdd(&lcur[b[i]], 1);
            int sidx = lbase[b[i]] + r;
            stage[sidx] = p[i];
            saddr[sidx] = gbaseS[b[i]] + r;
        }
    }
    __syncthreads();

    int tot = ltot;
    for (int s = tid; s < tot; s += 512) tmp[saddr[s]] = stage[s];
}

// -------- phase 4: per-bucket CSR (off, epair) + weighted deg -> dinv ------
__global__ __launch_bounds__(512) void partB_kernel(const uint2* __restrict__ tmp,
                                                    const int* __restrict__ gstart,
                                                    int2* __restrict__ epair,
                                                    int* __restrict__ off,
                                                    float* __restrict__ dinv,
                                                    int N) {
    __shared__ int   lhist[256], loff[256], lcur[256];
    __shared__ float ldeg[256];
    const int tid  = threadIdx.x;
    const int k    = blockIdx.x;
    const int seg0 = gstart[k], seg1 = gstart[k + 1];

    if (tid < 256) { lhist[tid] = 0; lcur[tid] = 0; ldeg[tid] = 0.f; }
    __syncthreads();

    for (int j = seg0 + tid; j < seg1; j += 512)
        atomicAdd(&lhist[tmp[j].y & 255u], 1);
    __syncthreads();

    if (tid < 64) {
        int b0 = tid * 4, v[4], s = 0;
#pragma unroll
        for (int t = 0; t < 4; ++t) { v[t] = s; s += lhist[b0 + t]; }
        int incl = s;
#pragma unroll
        for (int d = 1; d < 64; d <<= 1) {
            int t2 = __shfl_up(incl, d);
            if (tid >= d) incl += t2;
        }
        int excl = incl - s;
#pragma unroll
        for (int t = 0; t < 4; ++t) loff[b0 + t] = excl + v[t];
    }
    __syncthreads();

    if (tid < 256) {
        int d = (k << 8) + tid;
        if (d < N) off[d] = seg0 + loff[tid];
    }

    for (int j = seg0 + tid; j < seg1; j += 512) {
        uint2 q  = tmp[j];
        int dlow = q.y & 255u;
        int s    = (int)(q.y >> 8);
        float w  = __uint_as_float(q.x);
        int r    = atomicAdd(&lcur[dlow], 1);
        int2 pr; pr.x = s; pr.y = (int)q.x;
        epair[seg0 + loff[dlow] + r] = pr;   // scatter within 65KB window
        atomicAdd(&ldeg[dlow], w);
    }
    __syncthreads();

    if (tid < 256) {
        int d = (k << 8) + tid;
        if (d < N) dinv[d] = 1.0f / sqrtf(ldeg[tid] + 1.0f);
    }
}

// g1[N,32] = (x[N,128] @ W[128,32]) * dinv[node].  Block: 32 nodes.
__global__ __launch_bounds__(TPB) void gemm1_kernel(const float* __restrict__ x,
                                                    const float* __restrict__ W,
                                                    const float* __restrict__ dinv,
                                                    float* __restrict__ h, int N) {
    __shared__ float Ws[128 * 32];     // 16 KB
    __shared__ float xs[32 * 129];     // padded stride kills bank conflicts
    const int tid = threadIdx.x;
    const int nb  = blockIdx.x * 32;

    const float4* W4  = (const float4*)W;
    float4*       Ws4 = (float4*)Ws;
#pragma unroll
    for (int i = 0; i < 4; ++i) Ws4[tid + i * 256] = W4[tid + i * 256];

#pragma unroll
    for (int i = 0; i < 4; ++i) {
        int idx  = tid + i * 256;
        int node = idx >> 5;
        int col4 = idx & 31;
        if (nb + node < N) {
            float4 v = ((const float4*)(x + (size_t)nb * 128))[idx];
            float* p = &xs[node * 129 + col4 * 4];
            p[0] = v.x; p[1] = v.y; p[2] = v.z; p[3] = v.w;
        }
    }
    __syncthreads();

    const int nl = tid >> 3;
    const int og = (tid & 7) * 4;
    float a0 = 0.f, a1 = 0.f, a2 = 0.f, a3 = 0.f;
#pragma unroll 8
    for (int k = 0; k < 128; ++k) {
        float xv = xs[nl * 129 + k];
        const float* wp = &Ws[k * 32 + og];
        a0 = fmaf(xv, wp[0], a0);
        a1 = fmaf(xv, wp[1], a1);
        a2 = fmaf(xv, wp[2], a2);
        a3 = fmaf(xv, wp[3], a3);
    }
    int node = nb + nl;
    if (node < N) {
        float dv = dinv[node];
        float* out = &h[(size_t)node * 32 + og];
        out[0] = a0 * dv; out[1] = a1 * dv; out[2] = a2 * dv; out[3] = a3 * dv;
    }
}

// Pull-mode conv1 fused with relu, gemm2, the fc2 dot, AND the fc1 dot:
//   lanes 0-15: g2[f2] = hs*dv in regs -> z[i] = sum g2[f2]*fc1_w[f2]
//   lane 16+:   rdot[i] = hrelu . fc2_w[0:32]
// One wave handles NPW consecutive nodes; 4-deep unroll per half (TLP-bound).
// epair loads are NON-TEMPORAL to keep the stream out of L2.
__global__ __launch_bounds__(TPB) void gather32_fused_kernel(
    const int* __restrict__ off, const int2* __restrict__ epair,
    const float* __restrict__ g1, const float* __restrict__ dinv,
    const float* __restrict__ b1, const float* __restrict__ W2,
    const float* __restrict__ fc1_w, const float* __restrict__ fc2_w,
    float* __restrict__ z, float* __restrict__ rdot, int N, int E) {
    __shared__ float wls[560];  // [0..511]=W2, [512..543]=fc2_w, [544..559]=fc1_w
    const int tid = threadIdx.x;
    wls[tid]       = W2[tid];
    wls[tid + 256] = W2[tid + 256];
    if (tid < 32)      wls[512 + tid] = fc2_w[tid];
    else if (tid < 48) wls[512 + tid] = fc1_w[tid - 32];
    __syncthreads();

    const int lane = tid & 63;
    const int f    = lane & 31;
    const int half = lane >> 5;
    const float bv = b1[f];
    const int wbase = (lane < 16) ? lane : 512;   // W2 column | fc2_w
    const int wstrd = (lane < 16) ? 16 : 1;
    const float f1v = wls[544 + (lane & 15)];     // fc1_w[lane&15]

    const int i0 = (blockIdx.x * (TPB / 64) + (tid >> 6)) * NPW;

    for (int t = 0; t < NPW; ++t) {
        int i = i0 + t;
        if (i >= N) return;
        const int s0 = off[i];
        const int s1 = (i + 1 < N) ? off[i + 1] : E;

        float acc = 0.f;
        int j = s0 + half;
        for (; j + 6 < s1; j += 8) {           // 4-edge unroll per half
            int2 pa = ntload2(epair + j);
            int2 pb = ntload2(epair + j + 2);
            int2 pc = ntload2(epair + j + 4);
            int2 pd = ntload2(epair + j + 6);
            acc = fmaf(__int_as_float(pa.y), g1[(size_t)pa.x * 32 + f], acc);
            acc = fmaf(__int_as_float(pb.y), g1[(size_t)pb.x * 32 + f], acc);
            acc = fmaf(__int_as_float(pc.y), g1[(size_t)pc.x * 32 + f], acc);
            acc = fmaf(__int_as_float(pd.y), g1[(size_t)pd.x * 32 + f], acc);
        }
        for (; j < s1; j += 2) {
            int2 p = ntload2(epair + j);
            acc = fmaf(__int_as_float(p.y), g1[(size_t)p.x * 32 + f], acc);
        }
        acc += __shfl_xor(acc, 32);            // combine the two halves

        float dv = dinv[i];
        float v  = fmaxf(dv * (acc + g1[(size_t)i * 32 + f]) + bv, 0.f);

        // 32-step shfl matvec: lanes 0-15 -> h2[f2]; lanes >=16 -> rdot
        float hs = 0.f;
#pragma unroll
        for (int k = 0; k < 32; ++k)
            hs = fmaf(__shfl(v, k), wls[wbase + k * wstrd], hs);

        // fused zprep: z[i] = sum_{f2<16} (hs*dv)*fc1_w[f2]
        float zp = hs * dv * f1v;
        zp += __shfl_xor(zp, 1);
        zp += __shfl_xor(zp, 2);
        zp += __shfl_xor(zp, 4);
        zp += __shfl_xor(zp, 8);

        if (lane == 0)       z[i]    = zp;
        else if (lane == 16) rdot[i] = hs;
    }
}

// Scalar conv2 aggregation + full epilogue:
//   x1f = dinv*(sum_e w*z[src] + z[i]) + (b2.fc1_w + fc1_b)
//   c = sigmoid(x1f);  r = rdot[i] + c*fc2_w[32] + fc2_b
// One wave per NPW nodes; epair loads non-temporal (z stays cached).
__global__ __launch_bounds__(TPB) void final_scalar_kernel(
    const int* __restrict__ off, const int2* __restrict__ epair,
    const float* __restrict__ z, const float* __restrict__ rdot,
    const float* __restrict__ dinv, const float* __restrict__ b2,
    const float* __restrict__ fc1_w, const float* __restrict__ fc1_b,
    const float* __restrict__ fc2_w, const float* __restrict__ fc2_b,
    float* __restrict__ out, int N, int E) {
    const int tid  = threadIdx.x;
    const int lane = tid & 63;

    float C = fc1_b[0];
#pragma unroll
    for (int f = 0; f < 16; ++f) C = fmaf(b2[f], fc1_w[f], C);
    const float f2w = fc2_w[32];
    const float f2b = fc2_b[0];

    const int i0 = (blockIdx.x * (TPB / 64) + (tid >> 6)) * NPW;

    for (int t = 0; t < NPW; ++t) {
        int i = i0 + t;
        if (i >= N) return;
        const int s0 = off[i];
        const int s1 = (i + 1 < N) ? off[i + 1] : E;

        float acc = 0.f;
        for (int j = s0 + lane; j < s1; j += 64) {
            int2 p = ntload2(epair + j);
            acc = fmaf(__int_as_float(p.y), z[p.x], acc);
        }
        acc += __shfl_xor(acc, 1);
        acc += __shfl_xor(acc, 2);
        acc += __shfl_xor(acc, 4);
        acc += __shfl_xor(acc, 8);
        acc += __shfl_xor(acc, 16);
        acc += __shfl_xor(acc, 32);

        float x1f = dinv[i] * (acc + z[i]) + C;
        float c   = 1.0f / (1.0f + expf(-x1f));
        float r   = fmaf(c, f2w, f2b) + rdot[i];

        if (lane == 0) {
            out[i]     = r;
            out[N + i] = x1f;
        }
    }
}

extern "C" void kernel_launch(void* const* d_in, const int* in_sizes, int n_in,
                              void* d_out, int out_size, void* d_ws, size_t ws_size,
                              hipStream_t stream) {
    const float* x     = (const float*)d_in[0];
    const int*   ei    = (const int*)d_in[1];
    const float* ew    = (const float*)d_in[2];
    const float* W1    = (const float*)d_in[3];
    const float* b1    = (const float*)d_in[4];
    const float* W2    = (const float*)d_in[5];
    const float* b2    = (const float*)d_in[6];
    const float* fc1_w = (const float*)d_in[7];
    const float* fc1_b = (const float*)d_in[8];
    const float* fc2_w = (const float*)d_in[9];
    const float* fc2_b = (const float*)d_in[10];

    const int N = in_sizes[0] / 128;
    const int E = in_sizes[2];
    const int* src = ei;
    const int* dst = ei + E;
    const int K = (N + 255) >> 8;          // dst-buckets of 256 nodes

    // workspace (floats):
    //   dinv[N] | big[64N] (tmp overlay during build; later g1|rdot|z)
    //   | off[N] | epair[E] int2 | gcursor[K] | gstart[K+1]
    float* ws    = (float*)d_ws;
    float* dinv  = ws;
    float* big   = dinv + N;
    float* g1    = big;                            // 32N
    float* rdot  = big + (size_t)48 * N;           // N
    float* z     = big + (size_t)49 * N;           // N
    int*   off   = (int*)(big + (size_t)64 * N);
    int2*  epair = (int2*)(off + N);
    int*   gcursor = (int*)(epair + E);
    int*   gstart  = gcursor + K;
    uint2* tmp   = (uint2*)big;                    // E uint2 <= 64N floats

    size_t need = ((size_t)66 * N + (size_t)2 * E + 2 * K + 2) * 4;
    if (ws_size < need || K > KMAXB || (size_t)E > (size_t)32 * N) return;

    hipMemsetAsync(gcursor, 0, (size_t)K * sizeof(int), stream);

    countA_kernel<<<(E + PA_CHUNK - 1) / PA_CHUNK, 512, 0, stream>>>(dst, gcursor, E, K);
    kscan_kernel<<<1, 64, 0, stream>>>(gcursor, gstart, gcursor, K, E);
    placeA_kernel<<<(E + PA_CHUNK - 1) / PA_CHUNK, 512, 0, stream>>>(
        src, dst, ew, tmp, gcursor, E, K);
    partB_kernel<<<K, 512, 0, stream>>>(tmp, gstart, epair, off, dinv, N);

    gemm1_kernel<<<(N + 31) / 32, TPB, 0, stream>>>(x, W1, dinv, g1, N);

    const int gblocks = (N + 4 * NPW - 1) / (4 * NPW);   // 4 waves x NPW nodes
    gather32_fused_kernel<<<gblocks, TPB, 0, stream>>>(
        off, epair, g1, dinv, b1, W2, fc1_w, fc2_w, z, rdot, N, E);
    final_scalar_kernel<<<gblocks, TPB, 0, stream>>>(
        off, epair, z, rdot, dinv, b2, fc1_w, fc1_b, fc2_w, fc2_b,
        (float*)d_out, N, E);
}

// Round 15
// 349.758 us; speedup vs baseline: 1.0834x; 1.0834x over previous
//
#include <hip/hip_runtime.h>
#include <math.h>

// ---------------------------------------------------------------------------
// GCN: x[N,128] -> conv1(W1[128,32]) -> relu -> conv2(W2[32,16]) -> fc heads
// Outputs (concat): r[N], x1f[N]
//
// CSR-pull v9 RESTORED (verified 350.8 us in round 11) — the session best.
// Probe ledger: v10 8-deep unroll 376 (occupancy loss beats ILP gain);
// v11 fusedA+in-place-partB 359.6 (58 KB LDS occupancy loss); v12
// non-temporal epair loads 378.9 (FETCH 163->179 MB: the stream NEEDS L2
// line coalescing). All reverted.
// Structure: bucketed counting-sort CSR build (countA/kscan/placeA/partB),
// gemm1 with dinv epilogue, gather32 fused with {relu, W2 matvec, fc1 dot ->
// z, fc2 dot -> rdot}, and scalar conv2 (distributed fc1) + epilogue.
// Workspace: (66N + 2E + 2K + 2)*4 = 52.0 MB.
// ---------------------------------------------------------------------------

#define TPB 256
#define PA_CHUNK 4096
#define KMAXB 512
#define NPW 8              // nodes per wave in the gather kernels

// ---------------- phase 1: per-bucket edge counts --------------------------
__global__ __launch_bounds__(512) void countA_kernel(const int* __restrict__ dst,
                                                     int* __restrict__ gtot,
                                                     int E, int K) {
    __shared__ int lhist[KMAXB];
    const int tid = threadIdx.x;
    const int e0  = blockIdx.x * PA_CHUNK;
    if (tid < KMAXB) lhist[tid] = 0;
    __syncthreads();
#pragma unroll
    for (int i = 0; i < 8; ++i) {
        int e = e0 + tid + i * 512;
        if (e < E) atomicAdd(&lhist[dst[e] >> 8], 1);
    }
    __syncthreads();
    if (tid < K && lhist[tid] > 0) atomicAdd(&gtot[tid], lhist[tid]);
}

// ------- phase 2: scan totals -> gstart[K+1]; gcursor = gstart -------------
__global__ __launch_bounds__(64) void kscan_kernel(const int* __restrict__ gtot,
                                                   int* __restrict__ gstart,
                                                   int* __restrict__ gcursor,
                                                   int K, int E) {
    int tid = threadIdx.x;                  // one wave
    int b0 = tid * 8, v[8], s = 0;
#pragma unroll
    for (int t = 0; t < 8; ++t) {
        v[t] = s;
        int idx = b0 + t;
        s += (idx < K) ? gtot[idx] : 0;
    }
    int incl = s;
#pragma unroll
    for (int d = 1; d < 64; d <<= 1) {
        int t2 = __shfl_up(incl, d);
        if (tid >= d) incl += t2;
    }
    int excl = incl - s;
#pragma unroll
    for (int t = 0; t < 8; ++t) {
        int idx = b0 + t;
        if (idx < K) { gstart[idx] = excl + v[t]; gcursor[idx] = excl + v[t]; }
    }
    if (tid == 63) gstart[K] = E;
}

// ---------- phase 3: place edges into bucket-contiguous tmp ----------------
__global__ __launch_bounds__(512) void placeA_kernel(const int* __restrict__ src,
                                                     const int* __restrict__ dst,
                                                     const float* __restrict__ ew,
                                                     uint2* __restrict__ tmp,
                                                     int* __restrict__ gcursor,
                                                     int E, int K) {
    __shared__ int lhist[KMAXB], lbase[KMAXB], lcur[KMAXB], gbaseS[KMAXB];
    __shared__ int ltot;
    __shared__ uint2 stage[PA_CHUNK];
    __shared__ int   saddr[PA_CHUNK];
    const int tid = threadIdx.x;
    const int e0  = blockIdx.x * PA_CHUNK;

    if (tid < KMAXB) { lhist[tid] = 0; lcur[tid] = 0; }
    __syncthreads();

    int   b[8];
    uint2 p[8];
#pragma unroll
    for (int i = 0; i < 8; ++i) {
        int e = e0 + tid + i * 512;
        b[i] = -1;
        if (e < E) {
            int d   = dst[e];
            int s   = src[e];
            float w = ew[e];
            b[i]   = d >> 8;
            p[i].x = __float_as_uint(w);
            p[i].y = ((unsigned)s << 8) | (unsigned)(d & 255);
            atomicAdd(&lhist[b[i]], 1);
        }
    }
    __syncthreads();

    // exclusive scan lhist -> lbase (single wave, 8 bins/lane over 512)
    if (tid < 64) {
        int b0 = tid * 8, v[8], s = 0;
#pragma unroll
        for (int t = 0; t < 8; ++t) { v[t] = s; s += lhist[b0 + t]; }
        int incl = s;
#pragma unroll
        for (int d = 1; d < 64; d <<= 1) {
            int t2 = __shfl_up(incl, d);
            if (tid >= d) incl += t2;
        }
        int excl = incl - s;
#pragma unroll
        for (int t = 0; t < 8; ++t) lbase[b0 + t] = excl + v[t];
        if (tid == 63) ltot = incl;
    }
    __syncthreads();

    // reserve ABSOLUTE ranges from the based cursor (coalesced atomics)
    if (tid < K && lhist[tid] > 0)
        gbaseS[tid] = atomicAdd(&gcursor[tid], lhist[tid]);
    __syncthreads();

    // rank within (block,bucket), stage into LDS with absolute address
#pragma unroll
    for (int i = 0; i < 8; ++i) {
        if (b[i] >= 0) {
            int r    = atomicAdd(&lcur[b[i]], 1);
            int sidx = lbase[b[i]] + r;
            stage[sidx] = p[i];
            saddr[sidx] = gbaseS[b[i]] + r;
        }
    }
    __syncthreads();

    int tot = ltot;
    for (int s = tid; s < tot; s += 512) tmp[saddr[s]] = stage[s];
}

// -------- phase 4: per-bucket CSR (off, epair) + weighted deg -> dinv ------
__global__ __launch_bounds__(512) void partB_kernel(const uint2* __restrict__ tmp,
                                                    const int* __restrict__ gstart,
                                                    int2* __restrict__ epair,
                                                    int* __restrict__ off,
                                                    float* __restrict__ dinv,
                                                    int N) {
    __shared__ int   lhist[256], loff[256], lcur[256];
    __shared__ float ldeg[256];
    const int tid  = threadIdx.x;
    const int k    = blockIdx.x;
    const int seg0 = gstart[k], seg1 = gstart[k + 1];

    if (tid < 256) { lhist[tid] = 0; lcur[tid] = 0; ldeg[tid] = 0.f; }
    __syncthreads();

    for (int j = seg0 + tid; j < seg1; j += 512)
        atomicAdd(&lhist[tmp[j].y & 255u], 1);
    __syncthreads();

    if (tid < 64) {
        int b0 = tid * 4, v[4], s = 0;
#pragma unroll
        for (int t = 0; t < 4; ++t) { v[t] = s; s += lhist[b0 + t]; }
        int incl = s;
#pragma unroll
        for (int d = 1; d < 64; d <<= 1) {
            int t2 = __shfl_up(incl, d);
            if (tid >= d) incl += t2;
        }
        int excl = incl - s;
#pragma unroll
        for (int t = 0; t < 4; ++t) loff[b0 + t] = excl + v[t];
    }
    __syncthreads();

    if (tid < 256) {
        int d = (k << 8) + tid;
        if (d < N) off[d] = seg0 + loff[tid];
    }

    for (int j = seg0 + tid; j < seg1; j += 512) {
        uint2 q  = tmp[j];
        int dlow = q.y & 255u;
        int s    = (int)(q.y >> 8);
        float w  = __uint_as_float(q.x);
        int r    = atomicAdd(&lcur[dlow], 1);
        int2 pr; pr.x = s; pr.y = (int)q.x;
        epair[seg0 + loff[dlow] + r] = pr;   // scatter within 65KB window
        atomicAdd(&ldeg[dlow], w);
    }
    __syncthreads();

    if (tid < 256) {
        int d = (k << 8) + tid;
        if (d < N) dinv[d] = 1.0f / sqrtf(ldeg[tid] + 1.0f);
    }
}

// g1[N,32] = (x[N,128] @ W[128,32]) * dinv[node].  Block: 32 nodes.
__global__ __launch_bounds__(TPB) void gemm1_kernel(const float* __restrict__ x,
                                                    const float* __restrict__ W,
                                                    const float* __restrict__ dinv,
                                                    float* __restrict__ h, int N) {
    __shared__ float Ws[128 * 32];     // 16 KB
    __shared__ float xs[32 * 129];     // padded stride kills bank conflicts
    const int tid = threadIdx.x;
    const int nb  = blockIdx.x * 32;

    const float4* W4  = (const float4*)W;
    float4*       Ws4 = (float4*)Ws;
#pragma unroll
    for (int i = 0; i < 4; ++i) Ws4[tid + i * 256] = W4[tid + i * 256];

#pragma unroll
    for (int i = 0; i < 4; ++i) {
        int idx  = tid + i * 256;
        int node = idx >> 5;
        int col4 = idx & 31;
        if (nb + node < N) {
            float4 v = ((const float4*)(x + (size_t)nb * 128))[idx];
            float* p = &xs[node * 129 + col4 * 4];
            p[0] = v.x; p[1] = v.y; p[2] = v.z; p[3] = v.w;
        }
    }
    __syncthreads();

    const int nl = tid >> 3;
    const int og = (tid & 7) * 4;
    float a0 = 0.f, a1 = 0.f, a2 = 0.f, a3 = 0.f;
#pragma unroll 8
    for (int k = 0; k < 128; ++k) {
        float xv = xs[nl * 129 + k];
        const float* wp = &Ws[k * 32 + og];
        a0 = fmaf(xv, wp[0], a0);
        a1 = fmaf(xv, wp[1], a1);
        a2 = fmaf(xv, wp[2], a2);
        a3 = fmaf(xv, wp[3], a3);
    }
    int node = nb + nl;
    if (node < N) {
        float dv = dinv[node];
        float* out = &h[(size_t)node * 32 + og];
        out[0] = a0 * dv; out[1] = a1 * dv; out[2] = a2 * dv; out[3] = a3 * dv;
    }
}

// Pull-mode conv1 fused with relu, gemm2, the fc2 dot, AND the fc1 dot:
//   lanes 0-15: g2[f2] = hs*dv in regs -> z[i] = sum g2[f2]*fc1_w[f2]
//   lane 16+:   rdot[i] = hrelu . fc2_w[0:32]
// One wave handles NPW consecutive nodes; 4-deep unroll per half (TLP-bound,
// do NOT raise: 8-deep cost occupancy and regressed in round 10; nt loads
// regressed in round 14 — the stream needs L2 line coalescing).
__global__ __launch_bounds__(TPB) void gather32_fused_kernel(
    const int* __restrict__ off, const int2* __restrict__ epair,
    const float* __restrict__ g1, const float* __restrict__ dinv,
    const float* __restrict__ b1, const float* __restrict__ W2,
    const float* __restrict__ fc1_w, const float* __restrict__ fc2_w,
    float* __restrict__ z, float* __restrict__ rdot, int N, int E) {
    __shared__ float wls[560];  // [0..511]=W2, [512..543]=fc2_w, [544..559]=fc1_w
    const int tid = threadIdx.x;
    wls[tid]       = W2[tid];
    wls[tid + 256] = W2[tid + 256];
    if (tid < 32)      wls[512 + tid] = fc2_w[tid];
    else if (tid < 48) wls[512 + tid] = fc1_w[tid - 32];
    __syncthreads();

    const int lane = tid & 63;
    const int f    = lane & 31;
    const int half = lane >> 5;
    const float bv = b1[f];
    const int wbase = (lane < 16) ? lane : 512;   // W2 column | fc2_w
    const int wstrd = (lane < 16) ? 16 : 1;
    const float f1v = wls[544 + (lane & 15)];     // fc1_w[lane&15]

    const int i0 = (blockIdx.x * (TPB / 64) + (tid >> 6)) * NPW;

    for (int t = 0; t < NPW; ++t) {
        int i = i0 + t;
        if (i >= N) return;
        const int s0 = off[i];
        const int s1 = (i + 1 < N) ? off[i + 1] : E;

        float acc = 0.f;
        int j = s0 + half;
        for (; j + 6 < s1; j += 8) {           // 4-edge unroll per half
            int2 pa = epair[j];
            int2 pb = epair[j + 2];
            int2 pc = epair[j + 4];
            int2 pd = epair[j + 6];
            acc = fmaf(__int_as_float(pa.y), g1[(size_t)pa.x * 32 + f], acc);
            acc = fmaf(__int_as_float(pb.y), g1[(size_t)pb.x * 32 + f], acc);
            acc = fmaf(__int_as_float(pc.y), g1[(size_t)pc.x * 32 + f], acc);
            acc = fmaf(__int_as_float(pd.y), g1[(size_t)pd.x * 32 + f], acc);
        }
        for (; j < s1; j += 2) {
            int2 p = epair[j];
            acc = fmaf(__int_as_float(p.y), g1[(size_t)p.x * 32 + f], acc);
        }
        acc += __shfl_xor(acc, 32);            // combine the two halves

        float dv = dinv[i];
        float v  = fmaxf(dv * (acc + g1[(size_t)i * 32 + f]) + bv, 0.f);

        // 32-step shfl matvec: lanes 0-15 -> h2[f2]; lanes >=16 -> rdot
        float hs = 0.f;
#pragma unroll
        for (int k = 0; k < 32; ++k)
            hs = fmaf(__shfl(v, k), wls[wbase + k * wstrd], hs);

        // fused zprep: z[i] = sum_{f2<16} (hs*dv)*fc1_w[f2]
        float zp = hs * dv * f1v;
        zp += __shfl_xor(zp, 1);
        zp += __shfl_xor(zp, 2);
        zp += __shfl_xor(zp, 4);
        zp += __shfl_xor(zp, 8);

        if (lane == 0)       z[i]    = zp;
        else if (lane == 16) rdot[i] = hs;
    }
}

// Scalar conv2 aggregation + full epilogue:
//   x1f = dinv*(sum_e w*z[src] + z[i]) + (b2.fc1_w + fc1_b)
//   c = sigmoid(x1f);  r = rdot[i] + c*fc2_w[32] + fc2_b
// One wave per NPW nodes; 64 lanes stride each node's edge list.
__global__ __launch_bounds__(TPB) void final_scalar_kernel(
    const int* __restrict__ off, const int2* __restrict__ epair,
    const float* __restrict__ z, const float* __restrict__ rdot,
    const float* __restrict__ dinv, const float* __restrict__ b2,
    const float* __restrict__ fc1_w, const float* __restrict__ fc1_b,
    const float* __restrict__ fc2_w, const float* __restrict__ fc2_b,
    float* __restrict__ out, int N, int E) {
    const int tid  = threadIdx.x;
    const int lane = tid & 63;

    float C = fc1_b[0];
#pragma unroll
    for (int f = 0; f < 16; ++f) C = fmaf(b2[f], fc1_w[f], C);
    const float f2w = fc2_w[32];
    const float f2b = fc2_b[0];

    const int i0 = (blockIdx.x * (TPB / 64) + (tid >> 6)) * NPW;

    for (int t = 0; t < NPW; ++t) {
        int i = i0 + t;
        if (i >= N) return;
        const int s0 = off[i];
        const int s1 = (i + 1 < N) ? off[i + 1] : E;

        float acc = 0.f;
        for (int j = s0 + lane; j < s1; j += 64) {
            int2 p = epair[j];
            acc = fmaf(__int_as_float(p.y), z[p.x], acc);
        }
        acc += __shfl_xor(acc, 1);
        acc += __shfl_xor(acc, 2);
        acc += __shfl_xor(acc, 4);
        acc += __shfl_xor(acc, 8);
        acc += __shfl_xor(acc, 16);
        acc += __shfl_xor(acc, 32);

        float x1f = dinv[i] * (acc + z[i]) + C;
        float c   = 1.0f / (1.0f + expf(-x1f));
        float r   = fmaf(c, f2w, f2b) + rdot[i];

        if (lane == 0) {
            out[i]     = r;
            out[N + i] = x1f;
        }
    }
}

extern "C" void kernel_launch(void* const* d_in, const int* in_sizes, int n_in,
                              void* d_out, int out_size, void* d_ws, size_t ws_size,
                              hipStream_t stream) {
    const float* x     = (const float*)d_in[0];
    const int*   ei    = (const int*)d_in[1];
    const float* ew    = (const float*)d_in[2];
    const float* W1    = (const float*)d_in[3];
    const float* b1    = (const float*)d_in[4];
    const float* W2    = (const float*)d_in[5];
    const float* b2    = (const float*)d_in[6];
    const float* fc1_w = (const float*)d_in[7];
    const float* fc1_b = (const float*)d_in[8];
    const float* fc2_w = (const float*)d_in[9];
    const float* fc2_b = (const float*)d_in[10];

    const int N = in_sizes[0] / 128;
    const int E = in_sizes[2];
    const int* src = ei;
    const int* dst = ei + E;
    const int K = (N + 255) >> 8;          // dst-buckets of 256 nodes

    // workspace (floats):
    //   dinv[N] | big[64N] (tmp overlay during build; later g1|rdot|z)
    //   | off[N] | epair[E] int2 | gcursor[K] | gstart[K+1]
    float* ws    = (float*)d_ws;
    float* dinv  = ws;
    float* big   = dinv + N;
    float* g1    = big;                            // 32N
    float* rdot  = big + (size_t)48 * N;           // N
    float* z     = big + (size_t)49 * N;           // N
    int*   off   = (int*)(big + (size_t)64 * N);
    int2*  epair = (int2*)(off + N);
    int*   gcursor = (int*)(epair + E);
    int*   gstart  = gcursor + K;
    uint2* tmp   = (uint2*)big;                    // E uint2 <= 64N floats

    size_t need = ((size_t)66 * N + (size_t)2 * E + 2 * K + 2) * 4;
    if (ws_size < need || K > KMAXB || (size_t)E > (size_t)32 * N) return;

    hipMemsetAsync(gcursor, 0, (size_t)K * sizeof(int), stream);

    countA_kernel<<<(E + PA_CHUNK - 1) / PA_CHUNK, 512, 0, stream>>>(dst, gcursor, E, K);
    kscan_kernel<<<1, 64, 0, stream>>>(gcursor, gstart, gcursor, K, E);
    placeA_kernel<<<(E + PA_CHUNK - 1) / PA_CHUNK, 512, 0, stream>>>(
        src, dst, ew, tmp, gcursor, E, K);
    partB_kernel<<<K, 512, 0, stream>>>(tmp, gstart, epair, off, dinv, N);

    gemm1_kernel<<<(N + 31) / 32, TPB, 0, stream>>>(x, W1, dinv, g1, N);

    const int gblocks = (N + 4 * NPW - 1) / (4 * NPW);   // 4 waves x NPW nodes
    gather32_fused_kernel<<<gblocks, TPB, 0, stream>>>(
        off, epair, g1, dinv, b1, W2, fc1_w, fc2_w, z, rdot, N, E);
    final_scalar_kernel<<<gblocks, TPB, 0, stream>>>(
        off, epair, z, rdot, dinv, b2, fc1_w, fc1_b, fc2_w, fc2_b,
        (float*)d_out, N, E);
}